// Round 9
// baseline (70.663 us; speedup 1.0000x reference)
//
#include <hip/hip_runtime.h>

#define Hh 96
#define Ww 96
#define CIN 64
#define COUT 64
#define BATCH 8
#define HW 9216           // Hh*Ww
#define NOFF 18           // 2*K*K

// LDS layout (bytes) for k_main
#define XS_ROW   13824            // 96 px * 144B (128B data + 16B pad)
#define XS_SIZE  124416           // 9 rows
#define OF_BASE  124416           // offs [288 px][20 j] bf16 = 11520
#define SM_TOTAL 135936

typedef __attribute__((ext_vector_type(8))) short bf16x8;
typedef __attribute__((ext_vector_type(4))) float f32x4;
typedef __attribute__((ext_vector_type(2))) float f32x2;

__device__ inline ushort f2bf(float f) {
  union { float f; uint u; } v; v.f = f;
  uint u = v.u;
  u += 0x7FFF + ((u >> 16) & 1);     // RNE
  return (ushort)(u >> 16);
}
__device__ inline float bf2f(ushort s) {
  union { uint u; float f; } v; v.u = ((uint)s) << 16; return v.f;
}
__device__ inline uint cvtpk(float lo, float hi) {   // {bf(lo), bf(hi)}
  uint r;
  asm("v_cvt_pk_bf16_f32 %0, %1, %2" : "=v"(r) : "v"(lo), "v"(hi));
  return r;
}
__device__ inline f32x2 unpack2(uint u) {            // {f32(lo bf16), f32(hi bf16)}
  union { uint u[2]; f32x2 f; } r;
  r.u[0] = u << 16; r.u[1] = u & 0xFFFF0000u;
  return r.f;
}
__device__ inline f32x2 pkfma(f32x2 a, f32x2 b, f32x2 c) {
  f32x2 d;
  asm("v_pk_fma_f32 %0, %1, %2, %3" : "=v"(d) : "v"(a), "v"(b), "v"(c));
  return d;
}
__device__ inline f32x2 pkmul(f32x2 a, f32x2 b) {
  f32x2 d;
  asm("v_pk_mul_f32 %0, %1, %2" : "=v"(d) : "v"(a), "v"(b));
  return d;
}

// ---------------------------------------------------------------------------
// K0: pack weights wtb[k][o][c], wob[k][n(32)][c] (bf16).  216 blocks.
// ---------------------------------------------------------------------------
__global__ __launch_bounds__(256) void k_wpack(
    const float* __restrict__ w_def, const float* __restrict__ w_off,
    ushort* __restrict__ wtb, ushort* __restrict__ wob)
{
  int g = blockIdx.x * 256 + threadIdx.x;
  if (g < 36864) {
    int k = g >> 12, o = (g >> 6) & 63, c = g & 63;
    wtb[g] = f2bf(w_def[(o * 64 + c) * 9 + k]);
  }
  int g2 = g - 36864;
  if (g2 >= 0 && g2 < 18432) {
    int k = g2 >> 11, n = (g2 >> 6) & 31, c = g2 & 63;
    wob[g2] = (n < NOFF) ? f2bf(w_off[(n * 64 + c) * 9 + k]) : (ushort)0;
  }
}

// ---------------------------------------------------------------------------
// K1: fully-fused kernel.  256 blocks = 8 batches (XCD) x 32 row-triples,
// 768 threads (12 waves).  Stages x (NCHW f32 -> NHWC bf16 LDS tile, fused
// transpose+cvt).  Phase A: offset conv via MFMA, weights from global.
// Phase B: barrier-free 9-tap deform loop; gathers via ds_read_b128, B-frags
// from global (L1-hot).  Epilogue: LDS transpose, stores + BN partials.
// Task map: 36 tasks = 18 px-groups x 2 kh over 12 waves -> exactly 3/wave.
// ---------------------------------------------------------------------------
__global__ __launch_bounds__(768, 3) void k_main(
    const float* __restrict__ x, const ushort* __restrict__ wtb,
    const ushort* __restrict__ wob, const float* __restrict__ b_off,
    const float* __restrict__ b_def, float* __restrict__ out,
    float* __restrict__ parts)
{
  extern __shared__ char sm[];
  int tid = threadIdx.x;
  int bid = blockIdx.x;
  int b = bid & 7;                 // batch = XCD
  int rt = bid >> 3;
  int r0 = rt * 3;

  // ---- stage xs from NCHW f32 global (fused transpose + bf16 cvt) ----
  {
    const float* xb_g = x + (size_t)b * CIN * HW;
    int px = tid >> 3, cg = tid & 7;          // 768 = 96 px * 8 ch-groups
    #pragma unroll
    for (int s = 0; s < 9; ++s) {
      int srow = min(max(r0 - 3 + s, 0), 95);
      const float* src = xb_g + (size_t)(cg * 8) * HW + srow * 96 + px;
      float v[8];
      #pragma unroll
      for (int j = 0; j < 8; ++j) v[j] = src[(size_t)j * HW];
      uint u[4];
      u[0] = cvtpk(v[0], v[1]); u[1] = cvtpk(v[2], v[3]);
      u[2] = cvtpk(v[4], v[5]); u[3] = cvtpk(v[6], v[7]);
      *(uint4*)(sm + s * XS_ROW + px * 144 + cg * 16) = *(uint4*)u;
    }
  }
  __syncthreads();

  int wave = tid >> 6, lane = tid & 63;
  int m = lane & 15, hi = lane >> 4;
  int kh = wave & 1;
  int gb = wave >> 1;                       // 0..5
  int khB = kh * 64, hiB = hi * 16;
  int chE = kh * 32 + hi * 8;               // channel element offset

  // per-task geometry (g = gb + 6*ti < 18, always valid)
  int hA[3], wAc[3], pPix[3], gV[3];
  #pragma unroll
  for (int ti = 0; ti < 3; ++ti) {
    int g = gb + ti * 6;
    gV[ti] = g;
    int gr = g / 6, gc = g - gr * 6;
    hA[ti] = r0 + gr;
    wAc[ti] = gc * 16 + m;
    pPix[ti] = g * 16 + m;
  }

  // ---------------- Phase A: offset conv (K=32 per wave) -------------------
  f32x4 oacc[3][2];
  #pragma unroll
  for (int ti = 0; ti < 3; ++ti) {
    oacc[ti][0] = (f32x4){0.f, 0.f, 0.f, 0.f};
    oacc[ti][1] = (f32x4){0.f, 0.f, 0.f, 0.f};
  }
  for (int k = 0; k < 9; ++k) {
    int ky = k / 3 - 1, kx = (k - (k / 3) * 3) - 1;
    const ushort* wk = wob + k * 2048 + chE;
    bf16x8 wb0 = *(const bf16x8*)(wk + m * 64);
    bf16x8 wb1 = *(const bf16x8*)(wk + (16 + m) * 64);
    #pragma unroll
    for (int ti = 0; ti < 3; ++ti) {
      int yy = hA[ti] + ky, xx = wAc[ti] + kx;
      bool valid = (yy >= 0 && yy < Hh && xx >= 0 && xx < Ww);
      int cy = min(max(yy, 0), 95), cx = min(max(xx, 0), 95);
      int sy = cy - r0 + 3;
      bf16x8 a = *(const bf16x8*)(sm + sy * XS_ROW + cx * 144 + hiB + khB);
      if (!valid) a = (bf16x8)0;
      oacc[ti][0] = __builtin_amdgcn_mfma_f32_16x16x32_bf16(a, wb0, oacc[ti][0], 0, 0, 0);
      oacc[ti][1] = __builtin_amdgcn_mfma_f32_16x16x32_bf16(a, wb1, oacc[ti][1], 0, 0, 0);
    }
  }

  // offsets exchange via OF region: [pix][20 j] bf16
  int j0 = m, j1 = 16 + m;
  if (kh == 1) {
    #pragma unroll
    for (int ti = 0; ti < 3; ++ti) {
      #pragma unroll
      for (int r = 0; r < 4; ++r) {
        int p = gV[ti] * 16 + hi * 4 + r;
        *(ushort*)(sm + OF_BASE + p * 40 + j0 * 2) = f2bf(oacc[ti][0][r]);
        if (m < 2)
          *(ushort*)(sm + OF_BASE + p * 40 + j1 * 2) = f2bf(oacc[ti][1][r]);
      }
    }
  }
  __syncthreads();
  if (kh == 0) {
    float bo0 = b_off[j0];
    float bo1 = (m < 2) ? b_off[j1] : 0.f;
    #pragma unroll
    for (int ti = 0; ti < 3; ++ti) {
      #pragma unroll
      for (int r = 0; r < 4; ++r) {
        int p = gV[ti] * 16 + hi * 4 + r;
        ushort* a0p = (ushort*)(sm + OF_BASE + p * 40 + j0 * 2);
        *a0p = f2bf(oacc[ti][0][r] + bf2f(*a0p) + bo0);
        if (m < 2) {
          ushort* a1p = (ushort*)(sm + OF_BASE + p * 40 + j1 * 2);
          *a1p = f2bf(oacc[ti][1][r] + bf2f(*a1p) + bo1);
        }
      }
    }
  }
  __syncthreads();

  // ---------------- Phase B: barrier-free deform loop ----------------------
  f32x4 acc[3][4];
  #pragma unroll
  for (int ti = 0; ti < 3; ++ti)
    #pragma unroll
    for (int nt = 0; nt < 4; ++nt) acc[ti][nt] = (f32x4){0.f, 0.f, 0.f, 0.f};

  for (int k = 0; k < 9; ++k) {
    int ky = k / 3 - 1, kx = (k - (k / 3) * 3) - 1;
    // B-fragments straight from global (8KB/tap, L1-hot, wave-broadcast)
    const ushort* wk = wtb + k * 4096 + chE;
    bf16x8 bf0 = *(const bf16x8*)(wk + m * 64);
    bf16x8 bf1 = *(const bf16x8*)(wk + (16 + m) * 64);
    bf16x8 bf2 = *(const bf16x8*)(wk + (32 + m) * 64);
    bf16x8 bf3 = *(const bf16x8*)(wk + (48 + m) * 64);

    #pragma unroll
    for (int ti = 0; ti < 3; ++ti) {
      uint dd = *(const uint*)(sm + OF_BASE + pPix[ti] * 40 + k * 4);
      f32x2 dpair = unpack2(dd);
      float py = (float)(hA[ti] + ky) + dpair.x;
      float px = (float)(wAc[ti] + kx) + dpair.y;
      float y0f = floorf(py), x0f = floorf(px);
      float ly = py - y0f, lx = px - x0f;
      int y0 = (int)y0f, x0 = (int)x0f;
      int y1 = y0 + 1, x1 = x0 + 1;
      float fy0 = (y0 >= 0 && y0 < Hh) ? 1.f : 0.f;
      float fy1 = (y1 >= 0 && y1 < Hh) ? 1.f : 0.f;
      float fx0 = (x0 >= 0 && x0 < Ww) ? 1.f : 0.f;
      float fx1 = (x1 >= 0 && x1 < Ww) ? 1.f : 0.f;
      int cy0 = min(max(y0, 0), 95), cy1 = min(max(y1, 0), 95);
      int cx0 = min(max(x0, 0), 95), cx1 = min(max(x1, 0), 95);
      int sy0 = min(max(cy0 - r0 + 3, 0), 8);
      int sy1 = min(max(cy1 - r0 + 3, 0), 8);
      const char* row0 = sm + sy0 * XS_ROW;
      const char* row1 = sm + sy1 * XS_ROW;
      uint4 c00 = *(const uint4*)(row0 + cx0 * 144 + hiB + khB);
      uint4 c01 = *(const uint4*)(row0 + cx1 * 144 + hiB + khB);
      uint4 c10 = *(const uint4*)(row1 + cx0 * 144 + hiB + khB);
      uint4 c11 = *(const uint4*)(row1 + cx1 * 144 + hiB + khB);
      float s00 = (1.f - ly) * (1.f - lx) * (fy0 * fx0);
      float s01 = (1.f - ly) * lx * (fy0 * fx1);
      float s10 = ly * (1.f - lx) * (fy1 * fx0);
      float s11 = ly * lx * (fy1 * fx1);
      f32x2 w00 = (f32x2){s00, s00}, w01 = (f32x2){s01, s01};
      f32x2 w10 = (f32x2){s10, s10}, w11 = (f32x2){s11, s11};
      uint ua[4];
      {
        const uint* p00 = (const uint*)&c00; const uint* p01 = (const uint*)&c01;
        const uint* p10 = (const uint*)&c10; const uint* p11 = (const uint*)&c11;
        #pragma unroll
        for (int q = 0; q < 4; ++q) {
          f32x2 sv = pkmul(w00, unpack2(p00[q]));
          sv = pkfma(w01, unpack2(p01[q]), sv);
          sv = pkfma(w10, unpack2(p10[q]), sv);
          sv = pkfma(w11, unpack2(p11[q]), sv);
          ua[q] = cvtpk(sv.x, sv.y);
        }
      }
      bf16x8 av;
      __builtin_memcpy(&av, ua, 16);
      acc[ti][0] = __builtin_amdgcn_mfma_f32_16x16x32_bf16(av, bf0, acc[ti][0], 0, 0, 0);
      acc[ti][1] = __builtin_amdgcn_mfma_f32_16x16x32_bf16(av, bf1, acc[ti][1], 0, 0, 0);
      acc[ti][2] = __builtin_amdgcn_mfma_f32_16x16x32_bf16(av, bf2, acc[ti][2], 0, 0, 0);
      acc[ti][3] = __builtin_amdgcn_mfma_f32_16x16x32_bf16(av, bf3, acc[ti][3], 0, 0, 0);
    }
  }
  __syncthreads();   // all waves done reading xs before T aliases it

  // ---------------- epilogue: transpose via LDS (alias xs), store + BN -----
  float* T = (float*)sm;     // [64][289] f32
  if (kh == 1) {
    #pragma unroll
    for (int ti = 0; ti < 3; ++ti)
      #pragma unroll
      for (int nt = 0; nt < 4; ++nt) {
        int o = nt * 16 + m;
        #pragma unroll
        for (int r = 0; r < 4; ++r) {
          int p = gV[ti] * 16 + hi * 4 + r;
          T[o * 289 + p] = acc[ti][nt][r];
        }
      }
  }
  __syncthreads();
  if (kh == 0) {
    float bd[4];
    bd[0] = b_def[m]; bd[1] = b_def[16 + m];
    bd[2] = b_def[32 + m]; bd[3] = b_def[48 + m];
    #pragma unroll
    for (int ti = 0; ti < 3; ++ti)
      #pragma unroll
      for (int nt = 0; nt < 4; ++nt) {
        int o = nt * 16 + m;
        #pragma unroll
        for (int r = 0; r < 4; ++r) {
          int p = gV[ti] * 16 + hi * 4 + r;
          T[o * 289 + p] += acc[ti][nt][r] + bd[nt];
        }
      }
  }
  __syncthreads();
  if (tid < 512) {
    int o = tid >> 3, seg = tid & 7;
    const float* Tr = T + o * 289 + seg * 36;
    float* og = out + ((size_t)(b * 64 + o)) * HW + rt * 288 + seg * 36;
    float s = 0.f, ss = 0.f;
    #pragma unroll
    for (int j4 = 0; j4 < 9; ++j4) {
      float4 v;
      v.x = Tr[j4 * 4 + 0]; v.y = Tr[j4 * 4 + 1];
      v.z = Tr[j4 * 4 + 2]; v.w = Tr[j4 * 4 + 3];
      s += v.x + v.y + v.z + v.w;
      ss += v.x * v.x + v.y * v.y + v.z * v.z + v.w * v.w;
      *(float4*)(og + j4 * 4) = v;
    }
    s += __shfl_down(s, 4); s += __shfl_down(s, 2); s += __shfl_down(s, 1);
    ss += __shfl_down(ss, 4); ss += __shfl_down(ss, 2); ss += __shfl_down(ss, 1);
    if ((tid & 7) == 0) {
      parts[o * 256 + bid] = s;
      parts[16384 + o * 256 + bid] = ss;
    }
  }
}

// ---------------------------------------------------------------------------
// K3: finalize BN scale/shift.  64 blocks x 256 threads.
// ---------------------------------------------------------------------------
__global__ __launch_bounds__(256) void k_stats(
    const float* __restrict__ parts, const float* __restrict__ gamma,
    const float* __restrict__ beta, float* __restrict__ stats)
{
  int c = blockIdx.x;
  int tid = threadIdx.x;
  float s = 0.f, ss = 0.f;
  if (tid < 256) {
    s = parts[c * 256 + tid];
    ss = parts[16384 + c * 256 + tid];
  }
  #pragma unroll
  for (int off = 32; off >= 1; off >>= 1) {
    s += __shfl_down(s, off);
    ss += __shfl_down(ss, off);
  }
  __shared__ float rs[4], rss[4];
  int wave = tid >> 6, lane = tid & 63;
  if (lane == 0) { rs[wave] = s; rss[wave] = ss; }
  __syncthreads();
  if (tid == 0) {
    float S1 = rs[0] + rs[1] + rs[2] + rs[3];
    float S2 = rss[0] + rss[1] + rss[2] + rss[3];
    const float inv = 1.f / 73728.f;
    float mean = S1 * inv;
    float var = S2 * inv - mean * mean;
    float scale = gamma[c] * rsqrtf(var + 1e-5f);
    stats[c] = scale;
    stats[64 + c] = beta[c] - mean * scale;
  }
}

// ---------------------------------------------------------------------------
// K4: in-place normalize + affine + relu, float4 vectorized.
// ---------------------------------------------------------------------------
__global__ __launch_bounds__(256) void k_norm(
    float* __restrict__ out, const float* __restrict__ stats)
{
  int g = blockIdx.x * 256 + threadIdx.x;
  int o = (g / 2304) & 63;
  float sc = stats[o], sh = stats[64 + o];
  float4 v = ((const float4*)out)[g];
  v.x = fmaxf(fmaf(v.x, sc, sh), 0.f);
  v.y = fmaxf(fmaf(v.y, sc, sh), 0.f);
  v.z = fmaxf(fmaf(v.z, sc, sh), 0.f);
  v.w = fmaxf(fmaf(v.w, sc, sh), 0.f);
  ((float4*)out)[g] = v;
}

extern "C" void kernel_launch(void* const* d_in, const int* in_sizes, int n_in,
                              void* d_out, int out_size, void* d_ws, size_t ws_size,
                              hipStream_t stream) {
  const float* x     = (const float*)d_in[0];
  const float* w_off = (const float*)d_in[1];
  const float* b_off = (const float*)d_in[2];
  const float* w_def = (const float*)d_in[3];
  const float* b_def = (const float*)d_in[4];
  const float* gamma = (const float*)d_in[5];
  const float* beta  = (const float*)d_in[6];
  float* out = (float*)d_out;

  // workspace layout (float slots): wtb | wob | parts | stats
  float* base  = (float*)d_ws;
  ushort* wtb  = (ushort*)base;                    // 36864 bf16 (18432 slots)
  ushort* wob  = (ushort*)(base + 18432);          // 18432 bf16 (9216 slots)
  float* parts = base + 18432 + 9216;              // 32768
  float* stats = parts + 32768;                    // 128

  (void)hipFuncSetAttribute((const void*)k_main,
      hipFuncAttributeMaxDynamicSharedMemorySize, SM_TOTAL);

  k_wpack<<<216, 256, 0, stream>>>(w_def, w_off, wtb, wob);
  k_main<<<256, 768, SM_TOTAL, stream>>>(x, wtb, wob, b_off, b_def, out, parts);
  k_stats<<<64, 256, 0, stream>>>(parts, gamma, beta, stats);
  k_norm<<<4608, 256, 0, stream>>>(out, stats);
}

// Round 10
// 69.773 us; speedup vs baseline: 1.0128x; 1.0128x over previous
//
#include <hip/hip_runtime.h>

#define Hh 96
#define Ww 96
#define CIN 64
#define COUT 64
#define BATCH 8
#define HW 9216           // Hh*Ww
#define NOFF 18           // 2*K*K

// LDS layout (bytes) for k_main (col-tiled: 38 cols x 9 rows)
#define XS_ROW   5472             // 38 cols * 144B
#define XS_SIZE  49248            // 9 rows
#define WS_BASE  49248            // wob [9][18][144]=23328, then wtb [9][64][144]=82944
#define OF_BASE  132192           // offs [96 px][20 j] bf16 = 3840
#define SM_TOTAL 136032

typedef __attribute__((ext_vector_type(8))) short bf16x8;
typedef __attribute__((ext_vector_type(4))) float f32x4;
typedef __attribute__((ext_vector_type(2))) float f32x2;

__device__ inline ushort f2bf(float f) {
  union { float f; uint u; } v; v.f = f;
  uint u = v.u;
  u += 0x7FFF + ((u >> 16) & 1);     // RNE
  return (ushort)(u >> 16);
}
__device__ inline float bf2f(ushort s) {
  union { uint u; float f; } v; v.u = ((uint)s) << 16; return v.f;
}
__device__ inline uint cvtpk(float lo, float hi) {   // {bf(lo), bf(hi)}
  uint r;
  asm("v_cvt_pk_bf16_f32 %0, %1, %2" : "=v"(r) : "v"(lo), "v"(hi));
  return r;
}
__device__ inline f32x2 unpack2(uint u) {            // {f32(lo), f32(hi)}
  union { uint u[2]; f32x2 f; } r;
  r.u[0] = u << 16; r.u[1] = u & 0xFFFF0000u;
  return r.f;
}
__device__ inline f32x2 pkfma(f32x2 a, f32x2 b, f32x2 c) {
  f32x2 d;
  asm("v_pk_fma_f32 %0, %1, %2, %3" : "=v"(d) : "v"(a), "v"(b), "v"(c));
  return d;
}
__device__ inline f32x2 pkmul(f32x2 a, f32x2 b) {
  f32x2 d;
  asm("v_pk_mul_f32 %0, %1, %2" : "=v"(d) : "v"(a), "v"(b));
  return d;
}

// ---------------------------------------------------------------------------
// K0a: pack weights wtb[k][o][c], wob[k][n(32)][c] (bf16).  216 blocks.
// ---------------------------------------------------------------------------
__global__ __launch_bounds__(256) void k_wpack(
    const float* __restrict__ w_def, const float* __restrict__ w_off,
    ushort* __restrict__ wtb, ushort* __restrict__ wob)
{
  int g = blockIdx.x * 256 + threadIdx.x;
  if (g < 36864) {
    int k = g >> 12, o = (g >> 6) & 63, c = g & 63;
    wtb[g] = f2bf(w_def[(o * 64 + c) * 9 + k]);
  }
  int g2 = g - 36864;
  if (g2 >= 0 && g2 < 18432) {
    int k = g2 >> 11, n = (g2 >> 6) & 31, c = g2 & 63;
    wob[g2] = (n < NOFF) ? f2bf(w_off[(n * 64 + c) * 9 + k]) : (ushort)0;
  }
}

// ---------------------------------------------------------------------------
// K0b: transpose x (NCHW f32) -> xt (NHWC bf16) via padded LDS tile.
// ---------------------------------------------------------------------------
__global__ __launch_bounds__(256) void k_xt(
    const float* __restrict__ x, ushort* __restrict__ xt)
{
  __shared__ float tile[64][65];
  int tid = threadIdx.x;
  int blk = blockIdx.x;
  int b = blk / 144;
  int pbase = (blk - b * 144) * 64;
  int wave = tid >> 6, lane = tid & 63;
  const float* xp = x + (size_t)b * CIN * HW + pbase;
  #pragma unroll
  for (int i = 0; i < 16; ++i) {
    int c = wave * 16 + i;
    tile[lane][c] = xp[(size_t)c * HW + lane];
  }
  __syncthreads();
  ushort* xo = xt + ((size_t)b * HW + pbase) * 64;
  #pragma unroll
  for (int i = 0; i < 16; ++i) {
    int p = wave * 16 + i;
    xo[(size_t)p * 64 + lane] = f2bf(tile[p][lane]);
  }
}

// ---------------------------------------------------------------------------
// K1: fused tile kernel.  768 blocks = 8 batches (XCD) x 32 row-triples x 3
// col-tiles.  768 threads (12 waves), 1 task/wave (6 px-groups x 2 kh).
// Stage xs (9 rows x 38 cols, NHWC bf16, stride 144) + wob -> phase A offset
// conv (MFMA) -> offset exchange -> stage FULL wtb [9][64][144] (one shot)
// -> phase B: barrier-free 9-tap deform loop (all reads LDS) -> epilogue.
// ---------------------------------------------------------------------------
__global__ __launch_bounds__(768, 3) void k_main(
    const ushort* __restrict__ xt, const ushort* __restrict__ wtb,
    const ushort* __restrict__ wob, const float* __restrict__ b_off,
    const float* __restrict__ b_def, float* __restrict__ out,
    float* __restrict__ parts)
{
  extern __shared__ char sm[];
  int tid = threadIdx.x;
  int bid = blockIdx.x;
  int b = bid & 7;                 // batch = XCD
  int tile = bid >> 3;             // 0..95
  int rt = tile / 3, cs = tile - rt * 3;
  int r0 = rt * 3, c0 = cs * 32;

  // ---- stage xs: rows clamp(r0-3+s), cols clamp(c0-3+cl), s<9, cl<38 ----
  {
    const ushort* xsrc = xt + (size_t)b * HW * 64;
    for (int q = tid; q < 2736; q += 768) {
      int s = q / 304;
      int rem = q - s * 304;
      int cl = rem >> 3, cg = rem & 7;
      int srow = min(max(r0 - 3 + s, 0), 95);
      int scol = min(max(c0 - 3 + cl, 0), 95);
      uint4 v = *(const uint4*)(xsrc + (size_t)(srow * 96 + scol) * 64 + cg * 8);
      *(uint4*)(sm + s * XS_ROW + cl * 144 + cg * 16) = v;
    }
  }
  // ---- stage wob: [9][18][144] ----
  for (int q = tid; q < 1296; q += 768) {
    int k = q / 144;
    int rem = q - k * 144;
    int n = rem >> 3, cg = rem & 7;
    uint4 v = *(const uint4*)(wob + k * 2048 + n * 64 + cg * 8);
    *(uint4*)(sm + WS_BASE + k * 2592 + n * 144 + cg * 16) = v;
  }
  __syncthreads();

  int wave = tid >> 6, lane = tid & 63;
  int m = lane & 15, hi = lane >> 4;
  int kh = wave & 1;
  int pg = wave >> 1;                       // 0..5 : gr = pg>>1, gc = pg&1
  int khB = kh * 64, hiB = hi * 16;

  int hA = r0 + (pg >> 1);
  int wA = c0 + (pg & 1) * 16 + m;
  int p_pix = pg * 16 + m;                  // local pixel 0..95

  // ---------------- Phase A: offset conv (K=32 per wave) -------------------
  f32x4 oacc0 = (f32x4){0.f, 0.f, 0.f, 0.f};
  f32x4 oacc1 = (f32x4){0.f, 0.f, 0.f, 0.f};
  {
    int r1 = min(16 + m, 17);
    #pragma unroll
    for (int k = 0; k < 9; ++k) {
      int ky = k / 3 - 1, kx = (k - (k / 3) * 3) - 1;
      const char* wkb = sm + WS_BASE + k * 2592;
      bf16x8 wb0 = *(const bf16x8*)(wkb + m * 144 + hiB + khB);
      bf16x8 wb1 = *(const bf16x8*)(wkb + r1 * 144 + hiB + khB);
      int yy = hA + ky, xx = wA + kx;
      bool valid = (yy >= 0 && yy < Hh && xx >= 0 && xx < Ww);
      int sy = min(max(yy, 0), 95) - r0 + 3;
      int sx = min(max(xx, 0), 95) - c0 + 3;
      bf16x8 a = *(const bf16x8*)(sm + sy * XS_ROW + sx * 144 + hiB + khB);
      if (!valid) a = (bf16x8)0;
      oacc0 = __builtin_amdgcn_mfma_f32_16x16x32_bf16(a, wb0, oacc0, 0, 0, 0);
      oacc1 = __builtin_amdgcn_mfma_f32_16x16x32_bf16(a, wb1, oacc1, 0, 0, 0);
    }
  }

  // offsets exchange via OF region: [96 px][20 j] bf16
  int j0 = m, j1 = 16 + m;
  if (kh == 1) {
    #pragma unroll
    for (int r = 0; r < 4; ++r) {
      int p = pg * 16 + hi * 4 + r;
      *(ushort*)(sm + OF_BASE + p * 40 + j0 * 2) = f2bf(oacc0[r]);
      if (m < 2)
        *(ushort*)(sm + OF_BASE + p * 40 + j1 * 2) = f2bf(oacc1[r]);
    }
  }
  __syncthreads();
  // kh=0 folds in its half + bias; meanwhile all threads stage wtb (wob dead)
  if (kh == 0) {
    float bo0 = b_off[j0];
    float bo1 = (m < 2) ? b_off[j1] : 0.f;
    #pragma unroll
    for (int r = 0; r < 4; ++r) {
      int p = pg * 16 + hi * 4 + r;
      ushort* a0p = (ushort*)(sm + OF_BASE + p * 40 + j0 * 2);
      *a0p = f2bf(oacc0[r] + bf2f(*a0p) + bo0);
      if (m < 2) {
        ushort* a1p = (ushort*)(sm + OF_BASE + p * 40 + j1 * 2);
        *a1p = f2bf(oacc1[r] + bf2f(*a1p) + bo1);
      }
    }
  }
  // ---- stage FULL wtb: [9][64][144] = 82944B (one shot, overwrites wob) ----
  for (int q = tid; q < 4608; q += 768) {
    int k = q / 512;
    int rem = q - k * 512;
    int o = rem >> 3, cg = rem & 7;
    uint4 v = *(const uint4*)(wtb + k * 4096 + o * 64 + cg * 8);
    *(uint4*)(sm + WS_BASE + k * 9216 + o * 144 + cg * 16) = v;
  }
  __syncthreads();

  // ---------------- Phase B: barrier-free deform loop ----------------------
  f32x4 acc[4];
  #pragma unroll
  for (int nt = 0; nt < 4; ++nt) acc[nt] = (f32x4){0.f, 0.f, 0.f, 0.f};

  // prefetch all 9 taps' (dy,dx) pairs into registers
  uint od[9];
  #pragma unroll
  for (int k = 0; k < 9; ++k)
    od[k] = *(const uint*)(sm + OF_BASE + p_pix * 40 + k * 4);

  #pragma unroll 3
  for (int k = 0; k < 9; ++k) {
    int ky = k / 3 - 1, kx = (k - (k / 3) * 3) - 1;
    const char* wkb = sm + WS_BASE + k * 9216;
    bf16x8 bf0 = *(const bf16x8*)(wkb + m * 144 + hiB + khB);
    bf16x8 bf1 = *(const bf16x8*)(wkb + (16 + m) * 144 + hiB + khB);
    bf16x8 bf2 = *(const bf16x8*)(wkb + (32 + m) * 144 + hiB + khB);
    bf16x8 bf3 = *(const bf16x8*)(wkb + (48 + m) * 144 + hiB + khB);

    f32x2 dpair = unpack2(od[k]);
    float py = (float)(hA + ky) + dpair.x;
    float px = (float)(wA + kx) + dpair.y;
    float y0f = floorf(py), x0f = floorf(px);
    float ly = py - y0f, lx = px - x0f;
    int y0 = (int)y0f, x0 = (int)x0f;
    int y1 = y0 + 1, x1 = x0 + 1;
    float fy0 = (y0 >= 0 && y0 < Hh) ? 1.f : 0.f;
    float fy1 = (y1 >= 0 && y1 < Hh) ? 1.f : 0.f;
    float fx0 = (x0 >= 0 && x0 < Ww) ? 1.f : 0.f;
    float fx1 = (x1 >= 0 && x1 < Ww) ? 1.f : 0.f;
    int sy0 = min(max(min(max(y0, 0), 95) - r0 + 3, 0), 8);
    int sy1 = min(max(min(max(y1, 0), 95) - r0 + 3, 0), 8);
    int sx0 = min(max(min(max(x0, 0), 95) - c0 + 3, 0), 37);
    int sx1 = min(max(min(max(x1, 0), 95) - c0 + 3, 0), 37);
    const char* row0 = sm + sy0 * XS_ROW;
    const char* row1 = sm + sy1 * XS_ROW;
    uint4 c00 = *(const uint4*)(row0 + sx0 * 144 + hiB + khB);
    uint4 c01 = *(const uint4*)(row0 + sx1 * 144 + hiB + khB);
    uint4 c10 = *(const uint4*)(row1 + sx0 * 144 + hiB + khB);
    uint4 c11 = *(const uint4*)(row1 + sx1 * 144 + hiB + khB);
    float s00 = (1.f - ly) * (1.f - lx) * (fy0 * fx0);
    float s01 = (1.f - ly) * lx * (fy0 * fx1);
    float s10 = ly * (1.f - lx) * (fy1 * fx0);
    float s11 = ly * lx * (fy1 * fx1);
    f32x2 w00 = (f32x2){s00, s00}, w01 = (f32x2){s01, s01};
    f32x2 w10 = (f32x2){s10, s10}, w11 = (f32x2){s11, s11};
    uint ua[4];
    {
      const uint* p00 = (const uint*)&c00; const uint* p01 = (const uint*)&c01;
      const uint* p10 = (const uint*)&c10; const uint* p11 = (const uint*)&c11;
      #pragma unroll
      for (int q = 0; q < 4; ++q) {
        f32x2 sv = pkmul(w00, unpack2(p00[q]));
        sv = pkfma(w01, unpack2(p01[q]), sv);
        sv = pkfma(w10, unpack2(p10[q]), sv);
        sv = pkfma(w11, unpack2(p11[q]), sv);
        ua[q] = cvtpk(sv.x, sv.y);
      }
    }
    bf16x8 av;
    __builtin_memcpy(&av, ua, 16);
    acc[0] = __builtin_amdgcn_mfma_f32_16x16x32_bf16(av, bf0, acc[0], 0, 0, 0);
    acc[1] = __builtin_amdgcn_mfma_f32_16x16x32_bf16(av, bf1, acc[1], 0, 0, 0);
    acc[2] = __builtin_amdgcn_mfma_f32_16x16x32_bf16(av, bf2, acc[2], 0, 0, 0);
    acc[3] = __builtin_amdgcn_mfma_f32_16x16x32_bf16(av, bf3, acc[3], 0, 0, 0);
  }
  __syncthreads();   // everyone done reading xs/wtb before T aliases

  // ---------------- epilogue: combine kh halves via T, store + BN ----------
  float* T = (float*)sm;     // [64][97] f32 = 99328B (aliases xs+wtb)
  if (kh == 1) {
    #pragma unroll
    for (int nt = 0; nt < 4; ++nt) {
      int o = nt * 16 + m;
      #pragma unroll
      for (int r = 0; r < 4; ++r)
        T[o * 97 + pg * 16 + hi * 4 + r] = acc[nt][r];
    }
  }
  __syncthreads();
  if (kh == 0) {
    float bd[4];
    bd[0] = b_def[m]; bd[1] = b_def[16 + m];
    bd[2] = b_def[32 + m]; bd[3] = b_def[48 + m];
    #pragma unroll
    for (int nt = 0; nt < 4; ++nt) {
      int o = nt * 16 + m;
      #pragma unroll
      for (int r = 0; r < 4; ++r) {
        int p = pg * 16 + hi * 4 + r;
        T[o * 97 + p] += acc[nt][r] + bd[nt];
      }
    }
  }
  __syncthreads();
  if (tid < 512) {
    int o = tid >> 3, seg = tid & 7;     // 12 px per thread (3 float4)
    const float* Tr = T + o * 97 + seg * 12;
    float* og = out + (size_t)(b * 64 + o) * HW;
    float s = 0.f, ss = 0.f;
    #pragma unroll
    for (int j4 = 0; j4 < 3; ++j4) {
      int px = seg * 12 + j4 * 4;
      float4 v;
      v.x = Tr[j4 * 4 + 0]; v.y = Tr[j4 * 4 + 1];
      v.z = Tr[j4 * 4 + 2]; v.w = Tr[j4 * 4 + 3];
      s += v.x + v.y + v.z + v.w;
      ss += v.x * v.x + v.y * v.y + v.z * v.z + v.w * v.w;
      *(float4*)(og + (r0 + (px >> 5)) * 96 + c0 + (px & 31)) = v;
    }
    s += __shfl_down(s, 4); s += __shfl_down(s, 2); s += __shfl_down(s, 1);
    ss += __shfl_down(ss, 4); ss += __shfl_down(ss, 2); ss += __shfl_down(ss, 1);
    if ((tid & 7) == 0) {
      parts[o * 768 + bid] = s;
      parts[49152 + o * 768 + bid] = ss;
    }
  }
}

// ---------------------------------------------------------------------------
// K3: finalize BN scale/shift.  64 blocks x 256 threads.
// ---------------------------------------------------------------------------
__global__ __launch_bounds__(256) void k_stats(
    const float* __restrict__ parts, const float* __restrict__ gamma,
    const float* __restrict__ beta, float* __restrict__ stats)
{
  int c = blockIdx.x;
  int tid = threadIdx.x;
  float s = 0.f, ss = 0.f;
  for (int i = tid; i < 768; i += 256) {
    s += parts[c * 768 + i];
    ss += parts[49152 + c * 768 + i];
  }
  #pragma unroll
  for (int off = 32; off >= 1; off >>= 1) {
    s += __shfl_down(s, off);
    ss += __shfl_down(ss, off);
  }
  __shared__ float rs[4], rss[4];
  int wave = tid >> 6, lane = tid & 63;
  if (lane == 0) { rs[wave] = s; rss[wave] = ss; }
  __syncthreads();
  if (tid == 0) {
    float S1 = rs[0] + rs[1] + rs[2] + rs[3];
    float S2 = rss[0] + rss[1] + rss[2] + rss[3];
    const float inv = 1.f / 73728.f;
    float mean = S1 * inv;
    float var = S2 * inv - mean * mean;
    float scale = gamma[c] * rsqrtf(var + 1e-5f);
    stats[c] = scale;
    stats[64 + c] = beta[c] - mean * scale;
  }
}

// ---------------------------------------------------------------------------
// K4: in-place normalize + affine + relu, float4 vectorized.
// ---------------------------------------------------------------------------
__global__ __launch_bounds__(256) void k_norm(
    float* __restrict__ out, const float* __restrict__ stats)
{
  int g = blockIdx.x * 256 + threadIdx.x;
  int o = (g / 2304) & 63;
  float sc = stats[o], sh = stats[64 + o];
  float4 v = ((const float4*)out)[g];
  v.x = fmaxf(fmaf(v.x, sc, sh), 0.f);
  v.y = fmaxf(fmaf(v.y, sc, sh), 0.f);
  v.z = fmaxf(fmaf(v.z, sc, sh), 0.f);
  v.w = fmaxf(fmaf(v.w, sc, sh), 0.f);
  ((float4*)out)[g] = v;
}

extern "C" void kernel_launch(void* const* d_in, const int* in_sizes, int n_in,
                              void* d_out, int out_size, void* d_ws, size_t ws_size,
                              hipStream_t stream) {
  const float* x     = (const float*)d_in[0];
  const float* w_off = (const float*)d_in[1];
  const float* b_off = (const float*)d_in[2];
  const float* w_def = (const float*)d_in[3];
  const float* b_def = (const float*)d_in[4];
  const float* gamma = (const float*)d_in[5];
  const float* beta  = (const float*)d_in[6];
  float* out = (float*)d_out;

  // workspace layout (float slots): wtb | wob | xt | parts | stats
  float* base  = (float*)d_ws;
  ushort* wtb  = (ushort*)base;                    // 36864 bf16 (18432 slots)
  ushort* wob  = (ushort*)(base + 18432);          // 18432 bf16 (9216 slots)
  ushort* xt   = (ushort*)(base + 18432 + 9216);   // 4718592 bf16 (2359296 slots)
  float* parts = base + 18432 + 9216 + 2359296;    // 98304
  float* stats = parts + 98304;                    // 128

  (void)hipFuncSetAttribute((const void*)k_main,
      hipFuncAttributeMaxDynamicSharedMemorySize, SM_TOTAL);

  k_wpack<<<216, 256, 0, stream>>>(w_def, w_off, wtb, wob);
  k_xt<<<1152, 256, 0, stream>>>(x, xt);
  k_main<<<768, 768, SM_TOTAL, stream>>>(xt, wtb, wob, b_off, b_def, out, parts);
  k_stats<<<64, 256, 0, stream>>>(parts, gamma, beta, stats);
  k_norm<<<4608, 256, 0, stream>>>(out, stats);
}

// Round 14
// 60.009 us; speedup vs baseline: 1.1775x; 1.1627x over previous
//
#include <hip/hip_runtime.h>

#define Hh 96
#define Ww 96
#define CIN 64
#define COUT 64
#define BATCH 8
#define HW 9216           // Hh*Ww
#define NOFF 18           // 2*K*K

// LDS layout (bytes) for k_main
#define XS_ROW   13824            // 96 px * 144B (128B data + 16B pad)
#define XS_SIZE  124416           // 9 rows
#define WS_BASE  124416           // wob [9][18][144]=23328 ; later wtb dbuf [2][9216]
#define OF_BASE  147744           // offs [288 px][20 j] bf16 = 11520
#define SM_TOTAL 159264

typedef __attribute__((ext_vector_type(8))) short bf16x8;
typedef __attribute__((ext_vector_type(4))) float f32x4;

__device__ inline ushort f2bf(float f) {
  union { float f; uint u; } v; v.f = f;
  uint u = v.u;
  u += 0x7FFF + ((u >> 16) & 1);     // RNE
  return (ushort)(u >> 16);
}
__device__ inline float bf2f(ushort s) {
  union { uint u; float f; } v; v.u = ((uint)s) << 16; return v.f;
}
__device__ inline float bflo(uint u) {
  union { uint u; float f; } v; v.u = u << 16; return v.f;
}
__device__ inline float bfhi(uint u) {
  union { uint u; float f; } v; v.u = u & 0xFFFF0000u; return v.f;
}
__device__ inline uint cvtpk(float lo, float hi) {   // {bf(lo), bf(hi)} in 1 instr
  uint r;
  asm("v_cvt_pk_bf16_f32 %0, %1, %2" : "=v"(r) : "v"(lo), "v"(hi));
  return r;
}
__device__ inline uint interp_pack(uint p00, uint p01, uint p10, uint p11,
                                   float w00, float w01, float w10, float w11) {
  float vlo = fmaf(w11, bflo(p11), fmaf(w10, bflo(p10),
              fmaf(w01, bflo(p01), w00 * bflo(p00))));
  float vhi = fmaf(w11, bfhi(p11), fmaf(w10, bfhi(p10),
              fmaf(w01, bfhi(p01), w00 * bfhi(p00))));
  return cvtpk(vlo, vhi);
}

// ---------------------------------------------------------------------------
// K0: transpose x (NCHW f32) -> xt (NHWC bf16) via padded LDS tile, + pack
// weights (wtb [k][o][c], wob [k][n(32)][c]) in low blocks.
// ---------------------------------------------------------------------------
__global__ __launch_bounds__(256) void k_xt(
    const float* __restrict__ x, const float* __restrict__ w_def,
    const float* __restrict__ w_off, ushort* __restrict__ xt,
    ushort* __restrict__ wtb, ushort* __restrict__ wob)
{
  __shared__ float tile[64][65];
  int tid = threadIdx.x;
  int blk = blockIdx.x;

  if (blk < 9) {            // wtb[k][o][c] = bf16(w_def[o][c][k]), k = blk
    for (int i = tid; i < 4096; i += 256) {
      int o = i >> 6, c = i & 63;
      wtb[blk * 4096 + i] = f2bf(w_def[(o * 64 + c) * 9 + blk]);
    }
  } else if (blk < 25 && blk >= 16) {   // wob[k][n(32)][c], k = blk-16
    int k = blk - 16;
    for (int i = tid; i < 2048; i += 256) {
      int n = i >> 6, c = i & 63;
      wob[k * 2048 + i] = (n < NOFF) ? f2bf(w_off[(n * 64 + c) * 9 + k]) : (ushort)0;
    }
  }

  int b = blk / 144;
  int pbase = (blk - b * 144) * 64;
  int wave = tid >> 6, lane = tid & 63;
  const float* xp = x + (size_t)b * CIN * HW + pbase;
  #pragma unroll
  for (int i = 0; i < 16; ++i) {
    int c = wave * 16 + i;
    tile[lane][c] = xp[(size_t)c * HW + lane];
  }
  __syncthreads();
  ushort* xo = xt + ((size_t)b * HW + pbase) * 64;
  #pragma unroll
  for (int i = 0; i < 16; ++i) {
    int p = wave * 16 + i;
    xo[(size_t)p * 64 + lane] = f2bf(tile[p][lane]);
  }
}

// ---------------------------------------------------------------------------
// K1: fully-fused LDS-resident tile kernel.
// 256 blocks = 8 batches (XCD) x 32 row-triples.  768 threads (12 waves).
// Task map: 36 tasks = 18 px-groups x 2 kh; wave w: kh=w&1, gb=w>>1 (0..5),
// groups g = gb + 6*ti, ti<3  -> EXACTLY 3 tasks per wave (perfect balance).
// ---------------------------------------------------------------------------
__global__ __launch_bounds__(768, 3) void k_main(
    const ushort* __restrict__ xt, const ushort* __restrict__ wtb,
    const ushort* __restrict__ wob, const float* __restrict__ b_off,
    const float* __restrict__ b_def, float* __restrict__ out,
    float* __restrict__ parts)
{
  extern __shared__ char sm[];
  int tid = threadIdx.x;
  int bid = blockIdx.x;
  int b = bid & 7;                 // batch = XCD
  int rt = bid >> 3;
  int r0 = rt * 3;

  // ---- stage xs: rows clamp(r0-3+s) for s in [0,9) ----
  {
    const ushort* xsrc = xt + (size_t)b * HW * 64;
    for (int q = tid; q < 6912; q += 768) {
      int s = q / 768;
      int rem = q - s * 768;
      int cxp = rem >> 3, c16 = rem & 7;
      int srow = min(max(r0 - 3 + s, 0), 95);
      uint4 v = *(const uint4*)(xsrc + (size_t)(srow * 96 + cxp) * 64 + c16 * 8);
      *(uint4*)(sm + s * XS_ROW + cxp * 144 + c16 * 16) = v;
    }
  }
  // ---- stage wob: [9][18][144] ----
  for (int q = tid; q < 1296; q += 768) {
    int k = q / 144;
    int rem = q - k * 144;
    int n = rem >> 3, c16 = rem & 7;
    uint4 v = *(const uint4*)(wob + k * 2048 + n * 64 + c16 * 8);
    *(uint4*)(sm + WS_BASE + k * 2592 + n * 144 + c16 * 16) = v;
  }
  __syncthreads();

  int wave = tid >> 6, lane = tid & 63;
  int m = lane & 15, hi = lane >> 4;
  int kh = wave & 1;
  int gb = wave >> 1;                       // 0..5
  int khB = kh * 64, hiB = hi * 16;

  // per-task geometry (all valid: g = gb + 6*ti < 18)
  int hA[3], wAc[3], pPix[3], gV[3];
  #pragma unroll
  for (int ti = 0; ti < 3; ++ti) {
    int g = gb + ti * 6;
    gV[ti] = g;
    int gr = g / 6, gc = g - gr * 6;
    hA[ti] = r0 + gr;
    wAc[ti] = gc * 16 + m;
    pPix[ti] = g * 16 + m;
  }

  // ---------------- Phase A: offset conv (K=32 per wave) -------------------
  f32x4 oacc[3][2];
  #pragma unroll
  for (int ti = 0; ti < 3; ++ti) {
    oacc[ti][0] = (f32x4){0.f, 0.f, 0.f, 0.f};
    oacc[ti][1] = (f32x4){0.f, 0.f, 0.f, 0.f};
  }
  for (int k = 0; k < 9; ++k) {
    int ky = k / 3 - 1, kx = (k - (k / 3) * 3) - 1;
    const char* wkb = sm + WS_BASE + k * 2592;
    bf16x8 wb0 = *(const bf16x8*)(wkb + m * 144 + hiB + khB);
    int r1 = min(16 + m, 17);
    bf16x8 wb1 = *(const bf16x8*)(wkb + r1 * 144 + hiB + khB);
    #pragma unroll
    for (int ti = 0; ti < 3; ++ti) {
      int yy = hA[ti] + ky, xx = wAc[ti] + kx;
      bool valid = (yy >= 0 && yy < Hh && xx >= 0 && xx < Ww);
      int cy = min(max(yy, 0), 95), cx = min(max(xx, 0), 95);
      int sy = cy - r0 + 3;
      bf16x8 a = *(const bf16x8*)(sm + sy * XS_ROW + cx * 144 + hiB + khB);
      if (!valid) a = (bf16x8)0;
      oacc[ti][0] = __builtin_amdgcn_mfma_f32_16x16x32_bf16(a, wb0, oacc[ti][0], 0, 0, 0);
      oacc[ti][1] = __builtin_amdgcn_mfma_f32_16x16x32_bf16(a, wb1, oacc[ti][1], 0, 0, 0);
    }
  }

  // offsets exchange via OF region: [pix][20 j] bf16
  int j0 = m, j1 = 16 + m;
  if (kh == 1) {
    #pragma unroll
    for (int ti = 0; ti < 3; ++ti) {
      #pragma unroll
      for (int r = 0; r < 4; ++r) {
        int p = gV[ti] * 16 + hi * 4 + r;
        *(ushort*)(sm + OF_BASE + p * 40 + j0 * 2) = f2bf(oacc[ti][0][r]);
        if (m < 2)
          *(ushort*)(sm + OF_BASE + p * 40 + j1 * 2) = f2bf(oacc[ti][1][r]);
      }
    }
  }
  __syncthreads();
  if (kh == 0) {
    float bo0 = b_off[j0];
    float bo1 = (m < 2) ? b_off[j1] : 0.f;
    #pragma unroll
    for (int ti = 0; ti < 3; ++ti) {
      #pragma unroll
      for (int r = 0; r < 4; ++r) {
        int p = gV[ti] * 16 + hi * 4 + r;
        ushort* a0p = (ushort*)(sm + OF_BASE + p * 40 + j0 * 2);
        *a0p = f2bf(oacc[ti][0][r] + bf2f(*a0p) + bo0);
        if (m < 2) {
          ushort* a1p = (ushort*)(sm + OF_BASE + p * 40 + j1 * 2);
          *a1p = f2bf(oacc[ti][1][r] + bf2f(*a1p) + bo1);
        }
      }
    }
  }
  // stage wtb k=0 into dbuf slot 0 (overwrites wob region; phase A done)
  if (tid < 512) {
    int o = tid >> 3, c16 = tid & 7;
    uint4 v = *(const uint4*)(wtb + o * 64 + c16 * 8);
    *(uint4*)(sm + WS_BASE + o * 144 + c16 * 16) = v;
  }
  __syncthreads();

  // ---------------- Phase B: deform loop from LDS --------------------------
  f32x4 acc[3][4];
  #pragma unroll
  for (int ti = 0; ti < 3; ++ti)
    #pragma unroll
    for (int nt = 0; nt < 4; ++nt) acc[ti][nt] = (f32x4){0.f, 0.f, 0.f, 0.f};

  for (int k = 0; k < 9; ++k) {
    if (k < 8 && tid < 512) {    // prefetch next tap's w_def into other slot
      int o = tid >> 3, c16 = tid & 7;
      uint4 v = *(const uint4*)(wtb + (k + 1) * 4096 + o * 64 + c16 * 8);
      *(uint4*)(sm + WS_BASE + ((k + 1) & 1) * 9216 + o * 144 + c16 * 16) = v;
    }
    int ky = k / 3 - 1, kx = (k - (k / 3) * 3) - 1;
    const char* wkb = sm + WS_BASE + (k & 1) * 9216;
    bf16x8 bf0 = *(const bf16x8*)(wkb + m * 144 + hiB + khB);
    bf16x8 bf1 = *(const bf16x8*)(wkb + (16 + m) * 144 + hiB + khB);
    bf16x8 bf2 = *(const bf16x8*)(wkb + (32 + m) * 144 + hiB + khB);
    bf16x8 bf3 = *(const bf16x8*)(wkb + (48 + m) * 144 + hiB + khB);

    #pragma unroll
    for (int ti = 0; ti < 3; ++ti) {
      uint dd = *(const uint*)(sm + OF_BASE + pPix[ti] * 40 + k * 4);
      float dy = bflo(dd), dx = bfhi(dd);
      float py = (float)(hA[ti] + ky) + dy;
      float px = (float)(wAc[ti] + kx) + dx;
      float y0f = floorf(py), x0f = floorf(px);
      float ly = py - y0f, lx = px - x0f;
      int y0 = (int)y0f, x0 = (int)x0f;
      int y1 = y0 + 1, x1 = x0 + 1;
      float fy0 = (y0 >= 0 && y0 < Hh) ? 1.f : 0.f;
      float fy1 = (y1 >= 0 && y1 < Hh) ? 1.f : 0.f;
      float fx0 = (x0 >= 0 && x0 < Ww) ? 1.f : 0.f;
      float fx1 = (x1 >= 0 && x1 < Ww) ? 1.f : 0.f;
      int cy0 = min(max(y0, 0), 95), cy1 = min(max(y1, 0), 95);
      int cx0 = min(max(x0, 0), 95), cx1 = min(max(x1, 0), 95);
      int sy0 = min(max(cy0 - r0 + 3, 0), 8);
      int sy1 = min(max(cy1 - r0 + 3, 0), 8);
      const char* row0 = sm + sy0 * XS_ROW;
      const char* row1 = sm + sy1 * XS_ROW;
      uint4 c00 = *(const uint4*)(row0 + cx0 * 144 + hiB + khB);
      uint4 c01 = *(const uint4*)(row0 + cx1 * 144 + hiB + khB);
      uint4 c10 = *(const uint4*)(row1 + cx0 * 144 + hiB + khB);
      uint4 c11 = *(const uint4*)(row1 + cx1 * 144 + hiB + khB);
      float w00 = (1.f - ly) * (1.f - lx) * (fy0 * fx0);
      float w01 = (1.f - ly) * lx * (fy0 * fx1);
      float w10 = ly * (1.f - lx) * (fy1 * fx0);
      float w11 = ly * lx * (fy1 * fx1);
      uint ua[4];
      ua[0] = interp_pack(c00.x, c01.x, c10.x, c11.x, w00, w01, w10, w11);
      ua[1] = interp_pack(c00.y, c01.y, c10.y, c11.y, w00, w01, w10, w11);
      ua[2] = interp_pack(c00.z, c01.z, c10.z, c11.z, w00, w01, w10, w11);
      ua[3] = interp_pack(c00.w, c01.w, c10.w, c11.w, w00, w01, w10, w11);
      bf16x8 av;
      __builtin_memcpy(&av, ua, 16);
      acc[ti][0] = __builtin_amdgcn_mfma_f32_16x16x32_bf16(av, bf0, acc[ti][0], 0, 0, 0);
      acc[ti][1] = __builtin_amdgcn_mfma_f32_16x16x32_bf16(av, bf1, acc[ti][1], 0, 0, 0);
      acc[ti][2] = __builtin_amdgcn_mfma_f32_16x16x32_bf16(av, bf2, acc[ti][2], 0, 0, 0);
      acc[ti][3] = __builtin_amdgcn_mfma_f32_16x16x32_bf16(av, bf3, acc[ti][3], 0, 0, 0);
    }
    __syncthreads();
  }

  // ---------------- epilogue: transpose via LDS (alias xs), store + BN -----
  float* T = (float*)sm;     // [64][289] f32
  if (kh == 1) {
    #pragma unroll
    for (int ti = 0; ti < 3; ++ti)
      #pragma unroll
      for (int nt = 0; nt < 4; ++nt) {
        int o = nt * 16 + m;
        #pragma unroll
        for (int r = 0; r < 4; ++r) {
          int p = gV[ti] * 16 + hi * 4 + r;
          T[o * 289 + p] = acc[ti][nt][r];
        }
      }
  }
  __syncthreads();
  if (kh == 0) {
    float bd[4];
    bd[0] = b_def[m]; bd[1] = b_def[16 + m];
    bd[2] = b_def[32 + m]; bd[3] = b_def[48 + m];
    #pragma unroll
    for (int ti = 0; ti < 3; ++ti)
      #pragma unroll
      for (int nt = 0; nt < 4; ++nt) {
        int o = nt * 16 + m;
        #pragma unroll
        for (int r = 0; r < 4; ++r) {
          int p = gV[ti] * 16 + hi * 4 + r;
          T[o * 289 + p] += acc[ti][nt][r] + bd[nt];
        }
      }
  }
  __syncthreads();
  if (tid < 512) {
    int o = tid >> 3, seg = tid & 7;
    const float* Tr = T + o * 289 + seg * 36;
    float* og = out + ((size_t)(b * 64 + o)) * HW + rt * 288 + seg * 36;
    float s = 0.f, ss = 0.f;
    #pragma unroll
    for (int j4 = 0; j4 < 9; ++j4) {
      float4 v;
      v.x = Tr[j4 * 4 + 0]; v.y = Tr[j4 * 4 + 1];
      v.z = Tr[j4 * 4 + 2]; v.w = Tr[j4 * 4 + 3];
      s += v.x + v.y + v.z + v.w;
      ss += v.x * v.x + v.y * v.y + v.z * v.z + v.w * v.w;
      *(float4*)(og + j4 * 4) = v;
    }
    s += __shfl_down(s, 4); s += __shfl_down(s, 2); s += __shfl_down(s, 1);
    ss += __shfl_down(ss, 4); ss += __shfl_down(ss, 2); ss += __shfl_down(ss, 1);
    if ((tid & 7) == 0) {
      parts[o * 256 + bid] = s;
      parts[16384 + o * 256 + bid] = ss;
    }
  }
}

// ---------------------------------------------------------------------------
// K3: finalize BN scale/shift.  64 blocks x 256 threads.
// ---------------------------------------------------------------------------
__global__ __launch_bounds__(256) void k_stats(
    const float* __restrict__ parts, const float* __restrict__ gamma,
    const float* __restrict__ beta, float* __restrict__ stats)
{
  int c = blockIdx.x;
  int tid = threadIdx.x;
  float s = 0.f, ss = 0.f;
  for (int i = tid; i < 256; i += 256) {
    s += parts[c * 256 + i];
    ss += parts[16384 + c * 256 + i];
  }
  #pragma unroll
  for (int off = 32; off >= 1; off >>= 1) {
    s += __shfl_down(s, off);
    ss += __shfl_down(ss, off);
  }
  __shared__ float rs[4], rss[4];
  int wave = tid >> 6, lane = tid & 63;
  if (lane == 0) { rs[wave] = s; rss[wave] = ss; }
  __syncthreads();
  if (tid == 0) {
    float S1 = rs[0] + rs[1] + rs[2] + rs[3];
    float S2 = rss[0] + rss[1] + rss[2] + rss[3];
    const float inv = 1.f / 73728.f;
    float mean = S1 * inv;
    float var = S2 * inv - mean * mean;
    float scale = gamma[c] * rsqrtf(var + 1e-5f);
    stats[c] = scale;
    stats[64 + c] = beta[c] - mean * scale;
  }
}

// ---------------------------------------------------------------------------
// K4: in-place normalize + affine + relu, float4 vectorized.
// ---------------------------------------------------------------------------
__global__ __launch_bounds__(256) void k_norm(
    float* __restrict__ out, const float* __restrict__ stats)
{
  int g = blockIdx.x * 256 + threadIdx.x;
  int o = (g / 2304) & 63;
  float sc = stats[o], sh = stats[64 + o];
  float4 v = ((const float4*)out)[g];
  v.x = fmaxf(fmaf(v.x, sc, sh), 0.f);
  v.y = fmaxf(fmaf(v.y, sc, sh), 0.f);
  v.z = fmaxf(fmaf(v.z, sc, sh), 0.f);
  v.w = fmaxf(fmaf(v.w, sc, sh), 0.f);
  ((float4*)out)[g] = v;
}

extern "C" void kernel_launch(void* const* d_in, const int* in_sizes, int n_in,
                              void* d_out, int out_size, void* d_ws, size_t ws_size,
                              hipStream_t stream) {
  const float* x     = (const float*)d_in[0];
  const float* w_off = (const float*)d_in[1];
  const float* b_off = (const float*)d_in[2];
  const float* w_def = (const float*)d_in[3];
  const float* b_def = (const float*)d_in[4];
  const float* gamma = (const float*)d_in[5];
  const float* beta  = (const float*)d_in[6];
  float* out = (float*)d_out;

  // workspace layout (float slots): wtb | wob | xt | parts | stats
  float* base  = (float*)d_ws;
  ushort* wtb  = (ushort*)base;                    // 36864 bf16 (18432 slots)
  ushort* wob  = (ushort*)(base + 18432);          // 18432 bf16 (9216 slots)
  ushort* xt   = (ushort*)(base + 18432 + 9216);   // 4718592 bf16 (2359296 slots)
  float* parts = base + 18432 + 9216 + 2359296;    // 32768
  float* stats = parts + 32768;                    // 128

  (void)hipFuncSetAttribute((const void*)k_main,
      hipFuncAttributeMaxDynamicSharedMemorySize, SM_TOTAL);

  k_xt<<<1152, 256, 0, stream>>>(x, w_def, w_off, xt, wtb, wob);
  k_main<<<256, 768, SM_TOTAL, stream>>>(xt, wtb, wob, b_off, b_def, out, parts);
  k_stats<<<64, 256, 0, stream>>>(parts, gamma, beta, stats);
  k_norm<<<4608, 256, 0, stream>>>(out, stats);
}